// Round 5
// baseline (432.568 us; speedup 1.0000x reference)
//
#include <hip/hip_runtime.h>
#include <hip/hip_fp16.h>

#define TPB 256
#define CAP 16384          // slack entries per 256-node bucket (padded fill ~5100)
#define CAPSH 14           // log2(CAP)
#define SC_BLOCKS 256      // scatter blocks: contiguous pairs chunks per bucket
#define PB_BLOCKS 64       // perm-builder blocks
#define PB_CHUNK 784       // 64*784 = 50176 >= N (block-local counting sort)

typedef __attribute__((ext_vector_type(8))) float f32x8;
typedef __attribute__((ext_vector_type(8))) unsigned short u16x8;

// Identity used: dis⊙(x@W) = (dis⊙x)@W and Agg(z@W) = (Agg z)@W, so each
// layer is gather(z) -> mm -> relu, with z = fp16(dis ⊙ activation).
// Buckets: 256 nodes each (dst>>8); bucket b owns pairs/csr[b*CAP..).
// CSR runs padded to a multiple of 8 with index N (zero row).
// meta[v] = { (offset<<8) | nbatches, bitcast(dis) }.
// Lessons: R2 direct CSR build = 51MB write-allocate traffic (bad); R3 spill
// fix neutral (profiling artifact); R4 degree-binning neutral (divergence
// not the bottleneck). Pipe arithmetic says layers are LDS-return-BW bound:
// each wave re-reads ALL 16KB of W via 128 ds_read_b128 for only 8 nodes.
// This round: TWO nodes per 8-lane group. One W read feeds two FMA streams
// -> per-node LDS-pipe cycles drop ~44%. Per-node summation order is
// unchanged -> absmax bit-identical.

__device__ __forceinline__ int ld_idx(const void* p, long long i, int is64) {
    return is64 ? (int)((const long long*)p)[i] : ((const int*)p)[i];
}

__device__ __forceinline__ ushort4 f4_to_h4(float4 v) {
    ushort4 r;
    r.x = __half_as_ushort(__float2half_rn(v.x));
    r.y = __half_as_ushort(__float2half_rn(v.y));
    r.z = __half_as_ushort(__float2half_rn(v.z));
    r.w = __half_as_ushort(__float2half_rn(v.w));
    return r;
}

// ---------------------------------------------------------------------------
// Scatter: pass A histograms dst buckets (LDS), one global atomic per
// (block,bucket) reserves a contiguous chunk, pass B re-reads edges (L2/L3
// warm) and writes pairs into the chunk. gcur must be zeroed.
// ---------------------------------------------------------------------------
__global__ __launch_bounds__(TPB) void p3_scatter(const void* __restrict__ ei,
                                                  long long E,
                                                  int* __restrict__ gcur,
                                                  int* __restrict__ pairs) {
    __shared__ int cnt[TPB];
    __shared__ int cur2[TPB];
    __shared__ int s_is64;
    int t = threadIdx.x;
    if (t < 64) {
        const unsigned int* w = (const unsigned int*)ei;
        unsigned long long m = __ballot(w[2 * t + 1] != 0u);
        if (t == 0) s_is64 = (m == 0ull) ? 1 : 0;
    }
    cnt[t] = 0;
    __syncthreads();
    const int is64 = s_is64;
    long long chunk = (E + SC_BLOCKS - 1) / SC_BLOCKS;
    long long s0 = (long long)blockIdx.x * chunk;
    long long s1 = (s0 + chunk < E) ? s0 + chunk : E;

    for (long long e = s0 + t; e < s1; e += TPB) {       // pass A: count
        int d = ld_idx(ei, E + e, is64);
        atomicAdd(&cnt[d >> 8], 1);
    }
    __syncthreads();
    if (cnt[t]) cur2[t] = (t << CAPSH) + atomicAdd(&gcur[t], cnt[t]);
    __syncthreads();
    for (long long e = s0 + t; e < s1; e += TPB) {       // pass B: write
        int sv = ld_idx(ei, e, is64);
        int d  = ld_idx(ei, E + e, is64);
        int pos = atomicAdd(&cur2[d >> 8], 1);
        pairs[pos] = (sv << 8) | (d & 255);
    }
}

// ---------------------------------------------------------------------------
// One block per bucket: degree count (LDS atomics) -> pad-to-8 256-wide scan
// -> meta, csr scatter via LDS cursors + pad with index N, then
// z0 = fp16(dis * x) for this bucket's 256 nodes. Block 0 zeroes z0 row N.
// ---------------------------------------------------------------------------
__global__ __launch_bounds__(TPB) void p4_fill(const int* __restrict__ pairs,
                                               const int* __restrict__ gcur,
                                               const float* __restrict__ x,
                                               int2* __restrict__ meta,
                                               int* __restrict__ csr,
                                               ushort4* __restrict__ z0, int N) {
    __shared__ int ldeg[TPB];
    __shared__ int ssc[TPB];
    __shared__ int cur[TPB];
    __shared__ float fdis[TPB];
    int t = threadIdx.x;
    int b = blockIdx.x;
    int base = b << CAPSH;
    int ecnt = gcur[b];                          // real edges in this bucket
    ldeg[t] = 0;
    __syncthreads();
    for (int e = base + t; e < base + ecnt; e += TPB)
        atomicAdd(&ldeg[pairs[e] & 255], 1);
    __syncthreads();
    int dv = ldeg[t];
    int pv = (dv + 7) & ~7;                      // padded to multiple of 8
    ssc[t] = pv;
    __syncthreads();
    for (int off = 1; off < TPB; off <<= 1) {
        int u = 0;
        if (t >= off) u = ssc[t - off];
        __syncthreads();
        ssc[t] += u;
        __syncthreads();
    }
    int o = base + ssc[t] - pv;                  // absolute padded offset
    cur[t] = o;
    float dd = rsqrtf((float)(dv + 1));          // +1 self loop
    fdis[t] = dd;
    int node = (b << 8) + t;
    if (node < N)
        meta[node] = make_int2((o << 8) | (pv >> 3), __float_as_int(dd));
    __syncthreads();
    for (int e = base + t; e < base + ecnt; e += TPB) {
        int p = pairs[e];
        int pos = atomicAdd(&cur[p & 255], 1);
        csr[pos] = p >> 8;
    }
    for (int e = o + dv; e < o + pv; ++e) csr[e] = N;   // pad with zero row

    // z0 conversion: 16 passes, 16 nodes each, coalesced float4 reads.
    int ni = t >> 4, c = t & 15;
    for (int p = 0; p < 16; ++p) {
        int nd = (b << 8) + p * 16 + ni;
        if (nd < N) {
            float dvv = fdis[p * 16 + ni];
            float4 h = ((const float4*)x)[(size_t)nd * 16 + c];
            float4 r = {h.x * dvv, h.y * dvv, h.z * dvv, h.w * dvv};
            z0[(size_t)nd * 16 + c] = f4_to_h4(r);
        }
    }
    if (b == 0 && t < 16) z0[(size_t)N * 16 + t] = make_ushort4(0, 0, 0, 0);
}

// ---------------------------------------------------------------------------
// Degree-binned permutation: block-local counting sort of PB_CHUNK nodes by
// nbatch (= meta.x & 255). Keeps each wave's node-pairs at uniform gather
// trip counts. Tail slots filled with -1.
// ---------------------------------------------------------------------------
__global__ __launch_bounds__(TPB) void p5_perm(const int2* __restrict__ meta,
                                               int* __restrict__ perm,
                                               int N, int slots) {
    __shared__ int cnt[TPB];
    __shared__ int ssc[TPB];
    __shared__ int cur[TPB];
    int t = threadIdx.x;
    int s0 = blockIdx.x * PB_CHUNK;
    int s1 = s0 + PB_CHUNK < N ? s0 + PB_CHUNK : N;
    cnt[t] = 0;
    __syncthreads();
    for (int i = s0 + t; i < s1; i += TPB)
        atomicAdd(&cnt[meta[i].x & 255], 1);
    __syncthreads();
    int v = cnt[t];
    ssc[t] = v;
    __syncthreads();
    for (int off = 1; off < TPB; off <<= 1) {
        int u = 0;
        if (t >= off) u = ssc[t - off];
        __syncthreads();
        ssc[t] += u;
        __syncthreads();
    }
    cur[t] = s0 + ssc[t] - v;                    // block-local bin base
    __syncthreads();
    for (int i = s0 + t; i < s1; i += TPB) {
        int pos = atomicAdd(&cur[meta[i].x & 255], 1);
        perm[pos] = i;
    }
    if (s0 < N && s1 == N)                       // covering block fills tail
        for (int i = N + t; i < slots; i += TPB) perm[i] = -1;
}

// One 8-row gather batch for one node (8 lanes; lane c holds row-chunk c).
__device__ __forceinline__ void gather8(const u16x8* __restrict__ z8,
                                        int idx, int c, int base, f32x8& acc) {
    #pragma unroll
    for (int k = 0; k < 8; ++k) {
        int s = __shfl(idx, base + k);
        u16x8 v = z8[(size_t)s * 8 + c];
        #pragma unroll
        for (int i = 0; i < 8; ++i)
            acc[i] += __half2float(__ushort_as_half(v[i]));
    }
}

// Dual-node cooperative gather: interleaves node a and node b batches for
// 2x memory-level parallelism; next batch's CSR indices prefetched.
__device__ __forceinline__ void gather_pair(const u16x8* __restrict__ z8,
                                            const int* __restrict__ csr,
                                            int sa, int nba, int sb, int nbb,
                                            int c, f32x8& aa, f32x8& ab) {
    const int base = threadIdx.x & 56;           // 8-lane group base in wave
    int btmax = nba > nbb ? nba : nbb;
    int idxa = (nba > 0) ? csr[sa + c] : 0;
    int idxb = (nbb > 0) ? csr[sb + c] : 0;
    for (int bt = 0; bt < btmax; ++bt) {
        int nidxa = (bt + 1 < nba) ? csr[sa + (bt + 1) * 8 + c] : 0;
        int nidxb = (bt + 1 < nbb) ? csr[sb + (bt + 1) * 8 + c] : 0;
        if (bt < nba) gather8(z8, idxa, c, base, aa);
        if (bt < nbb) gather8(z8, idxb, c, base, ab);
        idxa = nidxa;
        idxb = nidxb;
    }
}

// Dual-node shfl mm: one W LDS read (2 float4s) feeds FMAs for BOTH nodes.
// Per-node LDS-return traffic halves vs the single-node version.
__device__ __forceinline__ void shfl_mm8_pair(const f32x8& sa, const f32x8& sb,
                                              const float4* Ws4, int c,
                                              f32x8& ua, f32x8& ub) {
    const int base = threadIdx.x & 56;
    #pragma unroll
    for (int q = 0; q < 8; ++q) {
        #pragma unroll
        for (int r = 0; r < 8; ++r) {
            float4 w0 = Ws4[(q * 8 + r) * 16 + 2 * c];
            float4 w1 = Ws4[(q * 8 + r) * 16 + 2 * c + 1];
            float ha = __shfl(sa[r], base + q);  // feature q*8+r, node a
            float hb = __shfl(sb[r], base + q);  // feature q*8+r, node b
            ua[0] = fmaf(ha, w0.x, ua[0]);  ub[0] = fmaf(hb, w0.x, ub[0]);
            ua[1] = fmaf(ha, w0.y, ua[1]);  ub[1] = fmaf(hb, w0.y, ub[1]);
            ua[2] = fmaf(ha, w0.z, ua[2]);  ub[2] = fmaf(hb, w0.z, ub[2]);
            ua[3] = fmaf(ha, w0.w, ua[3]);  ub[3] = fmaf(hb, w0.w, ub[3]);
            ua[4] = fmaf(ha, w1.x, ua[4]);  ub[4] = fmaf(hb, w1.x, ub[4]);
            ua[5] = fmaf(ha, w1.y, ua[5]);  ub[5] = fmaf(hb, w1.y, ub[5]);
            ua[6] = fmaf(ha, w1.z, ua[6]);  ub[6] = fmaf(hb, w1.z, ub[6]);
            ua[7] = fmaf(ha, w1.w, ua[7]);  ub[7] = fmaf(hb, w1.w, ub[7]);
        }
    }
}

__device__ __forceinline__ u16x8 f8_to_h8(f32x8 v) {
    u16x8 r;
    #pragma unroll
    for (int i = 0; i < 8; ++i)
        r[i] = __half_as_ushort(__float2half_rn(v[i]));
    return r;
}

__device__ __forceinline__ f32x8 relu_scale(const f32x8& u, float dv,
                                            float4 b0, float4 b1, float post) {
    f32x8 r;
    r[0] = fmaxf(fmaf(dv, u[0], b0.x), 0.f) * post;
    r[1] = fmaxf(fmaf(dv, u[1], b0.y), 0.f) * post;
    r[2] = fmaxf(fmaf(dv, u[2], b0.z), 0.f) * post;
    r[3] = fmaxf(fmaf(dv, u[3], b0.w), 0.f) * post;
    r[4] = fmaxf(fmaf(dv, u[4], b1.x), 0.f) * post;
    r[5] = fmaxf(fmaf(dv, u[5], b1.y), 0.f) * post;
    r[6] = fmaxf(fmaf(dv, u[6], b1.z), 0.f) * post;
    r[7] = fmaxf(fmaf(dv, u[7], b1.w), 0.f) * post;
    return r;
}

// ---------------------------------------------------------------------------
// Layer: s = z_v + Agg z_u (gather); u = s @ W; zout = fp16(dis*relu(dis*u+b)).
// 64 nodes/block: each 8-lane group owns TWO nodes (slots s0+g, s0+8+g).
// W in LDS (16 KB); one W read serves both nodes' FMA streams.
// ---------------------------------------------------------------------------
__global__ __launch_bounds__(TPB) void layer_mm(const u16x8* __restrict__ z,
                                                const int* __restrict__ csr,
                                                const int2* __restrict__ meta,
                                                const int* __restrict__ perm,
                                                const float* __restrict__ b,
                                                const float* __restrict__ W,
                                                u16x8* __restrict__ zout, int n) {
    __shared__ float Ws[64 * 64];
    int t = threadIdx.x;
    float4* Ws4 = (float4*)Ws;
    const float4* W4g = (const float4*)W;
    #pragma unroll
    for (int i = 0; i < 4; ++i) Ws4[t + i * TPB] = W4g[t + i * TPB];

    if (blockIdx.x == 0 && t < 8) {              // zero row N for next layer
        u16x8 zz = {0, 0, 0, 0, 0, 0, 0, 0};
        zout[(size_t)n * 8 + t] = zz;
    }

    int wave = t >> 6, lane = t & 63;
    int g = lane >> 3, c = lane & 7;
    int s0 = blockIdx.x * 64 + wave * 16;
    int na = perm[s0 + g];
    int nb = perm[s0 + 8 + g];
    f32x8 sa = {0.f, 0.f, 0.f, 0.f, 0.f, 0.f, 0.f, 0.f};
    f32x8 sb = {0.f, 0.f, 0.f, 0.f, 0.f, 0.f, 0.f, 0.f};
    float dva = 0.f, dvb = 0.f;
    int sta = 0, nba = 0, stb = 0, nbb = 0;
    if (na >= 0) {
        int2 m = meta[na];
        sta = ((unsigned)m.x) >> 8;
        nba = m.x & 255;
        dva = __int_as_float(m.y);
        u16x8 v = z[(size_t)na * 8 + c];         // self-loop term z_a
        #pragma unroll
        for (int i = 0; i < 8; ++i) sa[i] = __half2float(__ushort_as_half(v[i]));
    }
    if (nb >= 0) {
        int2 m = meta[nb];
        stb = ((unsigned)m.x) >> 8;
        nbb = m.x & 255;
        dvb = __int_as_float(m.y);
        u16x8 v = z[(size_t)nb * 8 + c];         // self-loop term z_b
        #pragma unroll
        for (int i = 0; i < 8; ++i) sb[i] = __half2float(__ushort_as_half(v[i]));
    }
    gather_pair(z, csr, sta, nba, stb, nbb, c, sa, sb);
    __syncthreads();                             // Ws fully staged
    f32x8 ua = {0.f, 0.f, 0.f, 0.f, 0.f, 0.f, 0.f, 0.f};
    f32x8 ub = {0.f, 0.f, 0.f, 0.f, 0.f, 0.f, 0.f, 0.f};
    shfl_mm8_pair(sa, sb, Ws4, c, ua, ub);
    float4 b0 = ((const float4*)b)[2 * c];
    float4 b1 = ((const float4*)b)[2 * c + 1];
    if (na >= 0) zout[(size_t)na * 8 + c] = f8_to_h8(relu_scale(ua, dva, b0, b1, dva));
    if (nb >= 0) zout[(size_t)nb * 8 + c] = f8_to_h8(relu_scale(ub, dvb, b0, b1, dvb));
}

// ---------------------------------------------------------------------------
// Final: s = gather(z2); h = relu(dis*(s@W2)+b2); out = h @ linW + linb.
// Dual-node like layer_mm; second mm (64->8) also shares Wls reads.
// ---------------------------------------------------------------------------
__global__ __launch_bounds__(TPB) void layer_final(const u16x8* __restrict__ z,
                                                   const int* __restrict__ csr,
                                                   const int2* __restrict__ meta,
                                                   const int* __restrict__ perm,
                                                   const float* __restrict__ b,
                                                   const float* __restrict__ W,
                                                   const float* __restrict__ Wl,
                                                   const float* __restrict__ bl,
                                                   float* __restrict__ out, int n) {
    __shared__ float Ws[64 * 64];
    __shared__ float Wls[64 * 8];
    __shared__ float bls[8];
    int t = threadIdx.x;
    float4* Ws4 = (float4*)Ws;
    const float4* W4g = (const float4*)W;
    #pragma unroll
    for (int i = 0; i < 4; ++i) Ws4[t + i * TPB] = W4g[t + i * TPB];
    if (t < 128) ((float4*)Wls)[t] = ((const float4*)Wl)[t];
    if (t < 8) bls[t] = bl[t];

    int wave = t >> 6, lane = t & 63;
    int g = lane >> 3, c = lane & 7;
    int s0 = blockIdx.x * 64 + wave * 16;
    int na = perm[s0 + g];
    int nb = perm[s0 + 8 + g];
    f32x8 sa = {0.f, 0.f, 0.f, 0.f, 0.f, 0.f, 0.f, 0.f};
    f32x8 sb = {0.f, 0.f, 0.f, 0.f, 0.f, 0.f, 0.f, 0.f};
    float dva = 0.f, dvb = 0.f;
    int sta = 0, nba = 0, stb = 0, nbb = 0;
    if (na >= 0) {
        int2 m = meta[na];
        sta = ((unsigned)m.x) >> 8;
        nba = m.x & 255;
        dva = __int_as_float(m.y);
        u16x8 v = z[(size_t)na * 8 + c];
        #pragma unroll
        for (int i = 0; i < 8; ++i) sa[i] = __half2float(__ushort_as_half(v[i]));
    }
    if (nb >= 0) {
        int2 m = meta[nb];
        stb = ((unsigned)m.x) >> 8;
        nbb = m.x & 255;
        dvb = __int_as_float(m.y);
        u16x8 v = z[(size_t)nb * 8 + c];
        #pragma unroll
        for (int i = 0; i < 8; ++i) sb[i] = __half2float(__ushort_as_half(v[i]));
    }
    gather_pair(z, csr, sta, nba, stb, nbb, c, sa, sb);
    __syncthreads();                             // Ws/Wls/bls staged
    f32x8 ua = {0.f, 0.f, 0.f, 0.f, 0.f, 0.f, 0.f, 0.f};
    f32x8 ub = {0.f, 0.f, 0.f, 0.f, 0.f, 0.f, 0.f, 0.f};
    shfl_mm8_pair(sa, sb, Ws4, c, ua, ub);
    float4 b0 = ((const float4*)b)[2 * c];
    float4 b1 = ((const float4*)b)[2 * c + 1];
    f32x8 ha = relu_scale(ua, dva, b0, b1, 1.f);
    f32x8 hb = relu_scale(ub, dvb, b0, b1, 1.f);

    // second mm (64 -> 8): lane c computes output col c for both nodes.
    const int base = t & 56;
    float acca = bls[c], accb = bls[c];
    #pragma unroll
    for (int q = 0; q < 8; ++q) {
        #pragma unroll
        for (int r = 0; r < 8; ++r) {
            float wv = Wls[(q * 8 + r) * 8 + c];
            float va = __shfl(ha[r], base + q);  // feature q*8+r, node a
            float vb = __shfl(hb[r], base + q);
            acca = fmaf(va, wv, acca);
            accb = fmaf(vb, wv, accb);
        }
    }
    if (na >= 0) out[(size_t)na * 8 + c] = acca;
    if (nb >= 0) out[(size_t)nb * 8 + c] = accb;
}

extern "C" void kernel_launch(void* const* d_in, const int* in_sizes, int n_in,
                              void* d_out, int out_size, void* d_ws, size_t ws_size,
                              hipStream_t stream) {
    const float* x  = (const float*)d_in[0];
    const void*  ei = d_in[1];
    const float* W0 = (const float*)d_in[2];
    const float* b0 = (const float*)d_in[3];
    const float* W1 = (const float*)d_in[4];
    const float* b1 = (const float*)d_in[5];
    const float* W2 = (const float*)d_in[6];
    const float* b2 = (const float*)d_in[7];
    const float* Wl = (const float*)d_in[8];
    const float* bl = (const float*)d_in[9];

    const long long E = in_sizes[1] / 2;                 // 800000
    const int dh = in_sizes[3];                          // 64
    const int din = in_sizes[2] / dh;                    // 64
    const int N = in_sizes[0] / din;                     // 50000
    const int nb = (N + 255) >> 8;                       // 196 buckets
    const int gL = (N + 63) / 64;                        // 782 (64 nodes/block)
    const int slots = gL * 64;                           // 50048

    // Workspace carve (256-aligned): ~39.4 MB total
    char* ws = (char*)d_ws;
    size_t off = 0;
    auto alloc = [&](size_t bytes) -> char* {
        char* r = ws + off;
        off += (bytes + 255) & ~(size_t)255;
        return r;
    };
    int*   gcur    = (int*)  alloc(1024);
    int2*  meta    = (int2*) alloc((size_t)N * 8);
    int*   perm    = (int*)  alloc((size_t)slots * 4);
    int*   pairs   = (int*)  alloc((size_t)nb * CAP * 4);       // 12.8 MB
    int*   csr     = (int*)  alloc((size_t)nb * CAP * 4);       // 12.8 MB
    u16x8* zbA     = (u16x8*)alloc((size_t)(N + 1) * 64 * 2);   // fp16 rows (+zero row)
    u16x8* zbB     = (u16x8*)alloc((size_t)(N + 1) * 64 * 2);

    // --- preprocessing ---
    hipMemsetAsync(gcur, 0, 256 * sizeof(int), stream);
    p3_scatter<<<SC_BLOCKS, TPB, 0, stream>>>(ei, E, gcur, pairs);
    p4_fill<<<nb, TPB, 0, stream>>>(pairs, gcur, x, meta, csr,
                                    (ushort4*)zbA, N);
    p5_perm<<<PB_BLOCKS, TPB, 0, stream>>>(meta, perm, N, slots);

    // --- 3 layers: gather -> mm -> relu ---
    layer_mm<<<gL, TPB, 0, stream>>>(zbA, csr, meta, perm, b0, W0, zbB, N);
    layer_mm<<<gL, TPB, 0, stream>>>(zbB, csr, meta, perm, b1, W1, zbA, N);
    layer_final<<<gL, TPB, 0, stream>>>(zbA, csr, meta, perm, b2, W2, Wl, bl,
                                        (float*)d_out, N);
}

// Round 6
// 199.045 us; speedup vs baseline: 2.1732x; 2.1732x over previous
//
#include <hip/hip_runtime.h>
#include <hip/hip_fp16.h>

#define TPB 256
#define CAP 16384          // slack entries per 256-node bucket (padded fill ~5100)
#define CAPSH 14           // log2(CAP)
#define SC_BLOCKS 256      // scatter blocks: contiguous pairs chunks per bucket
#define PB_BLOCKS 64       // perm-builder blocks
#define PB_CHUNK 784       // 64*784 = 50176 >= N (block-local counting sort)

typedef __attribute__((ext_vector_type(8))) float f32x8;
typedef __attribute__((ext_vector_type(8))) unsigned short u16x8;

// Identity used: dis⊙(x@W) = (dis⊙x)@W and Agg(z@W) = (Agg z)@W, so each
// layer is gather(z) -> mm -> relu, with z = fp16(dis ⊙ activation).
// Buckets: 256 nodes each (dst>>8); bucket b owns pairs/csr[b*CAP..).
// CSR runs padded to a multiple of 8 with index N (zero row).
// meta[v] = { (offset<<8) | nbatches, bitcast(dis) }.
// Lessons: R2 direct CSR = 51MB write-allocate (bad). R3 spill fix neutral.
// R4 degree-binning neutral. R5 dual-node spilled to scratch (VGPR=256,
// 124MB scratch writes/dispatch, 143us/layer): the fully-unrolled 64-step
// (q,r) loop let the scheduler hoist 128 ds_read_b128 -> register blowup.
// This round: SAME dual-node structure (one W read feeds two FMA streams,
// halving per-node LDS W traffic) with the spill fixed: q-loop unroll
// capped at 2, and __launch_bounds__(256,3) capping VGPR at ~168.

__device__ __forceinline__ int ld_idx(const void* p, long long i, int is64) {
    return is64 ? (int)((const long long*)p)[i] : ((const int*)p)[i];
}

__device__ __forceinline__ ushort4 f4_to_h4(float4 v) {
    ushort4 r;
    r.x = __half_as_ushort(__float2half_rn(v.x));
    r.y = __half_as_ushort(__float2half_rn(v.y));
    r.z = __half_as_ushort(__float2half_rn(v.z));
    r.w = __half_as_ushort(__float2half_rn(v.w));
    return r;
}

// ---------------------------------------------------------------------------
// Scatter: pass A histograms dst buckets (LDS), one global atomic per
// (block,bucket) reserves a contiguous chunk, pass B re-reads edges (L2/L3
// warm) and writes pairs into the chunk. gcur must be zeroed.
// ---------------------------------------------------------------------------
__global__ __launch_bounds__(TPB) void p3_scatter(const void* __restrict__ ei,
                                                  long long E,
                                                  int* __restrict__ gcur,
                                                  int* __restrict__ pairs) {
    __shared__ int cnt[TPB];
    __shared__ int cur2[TPB];
    __shared__ int s_is64;
    int t = threadIdx.x;
    if (t < 64) {
        const unsigned int* w = (const unsigned int*)ei;
        unsigned long long m = __ballot(w[2 * t + 1] != 0u);
        if (t == 0) s_is64 = (m == 0ull) ? 1 : 0;
    }
    cnt[t] = 0;
    __syncthreads();
    const int is64 = s_is64;
    long long chunk = (E + SC_BLOCKS - 1) / SC_BLOCKS;
    long long s0 = (long long)blockIdx.x * chunk;
    long long s1 = (s0 + chunk < E) ? s0 + chunk : E;

    for (long long e = s0 + t; e < s1; e += TPB) {       // pass A: count
        int d = ld_idx(ei, E + e, is64);
        atomicAdd(&cnt[d >> 8], 1);
    }
    __syncthreads();
    if (cnt[t]) cur2[t] = (t << CAPSH) + atomicAdd(&gcur[t], cnt[t]);
    __syncthreads();
    for (long long e = s0 + t; e < s1; e += TPB) {       // pass B: write
        int sv = ld_idx(ei, e, is64);
        int d  = ld_idx(ei, E + e, is64);
        int pos = atomicAdd(&cur2[d >> 8], 1);
        pairs[pos] = (sv << 8) | (d & 255);
    }
}

// ---------------------------------------------------------------------------
// One block per bucket: degree count (LDS atomics) -> pad-to-8 256-wide scan
// -> meta, csr scatter via LDS cursors + pad with index N, then
// z0 = fp16(dis * x) for this bucket's 256 nodes. Block 0 zeroes z0 row N.
// ---------------------------------------------------------------------------
__global__ __launch_bounds__(TPB) void p4_fill(const int* __restrict__ pairs,
                                               const int* __restrict__ gcur,
                                               const float* __restrict__ x,
                                               int2* __restrict__ meta,
                                               int* __restrict__ csr,
                                               ushort4* __restrict__ z0, int N) {
    __shared__ int ldeg[TPB];
    __shared__ int ssc[TPB];
    __shared__ int cur[TPB];
    __shared__ float fdis[TPB];
    int t = threadIdx.x;
    int b = blockIdx.x;
    int base = b << CAPSH;
    int ecnt = gcur[b];                          // real edges in this bucket
    ldeg[t] = 0;
    __syncthreads();
    for (int e = base + t; e < base + ecnt; e += TPB)
        atomicAdd(&ldeg[pairs[e] & 255], 1);
    __syncthreads();
    int dv = ldeg[t];
    int pv = (dv + 7) & ~7;                      // padded to multiple of 8
    ssc[t] = pv;
    __syncthreads();
    for (int off = 1; off < TPB; off <<= 1) {
        int u = 0;
        if (t >= off) u = ssc[t - off];
        __syncthreads();
        ssc[t] += u;
        __syncthreads();
    }
    int o = base + ssc[t] - pv;                  // absolute padded offset
    cur[t] = o;
    float dd = rsqrtf((float)(dv + 1));          // +1 self loop
    fdis[t] = dd;
    int node = (b << 8) + t;
    if (node < N)
        meta[node] = make_int2((o << 8) | (pv >> 3), __float_as_int(dd));
    __syncthreads();
    for (int e = base + t; e < base + ecnt; e += TPB) {
        int p = pairs[e];
        int pos = atomicAdd(&cur[p & 255], 1);
        csr[pos] = p >> 8;
    }
    for (int e = o + dv; e < o + pv; ++e) csr[e] = N;   // pad with zero row

    // z0 conversion: 16 passes, 16 nodes each, coalesced float4 reads.
    int ni = t >> 4, c = t & 15;
    for (int p = 0; p < 16; ++p) {
        int nd = (b << 8) + p * 16 + ni;
        if (nd < N) {
            float dvv = fdis[p * 16 + ni];
            float4 h = ((const float4*)x)[(size_t)nd * 16 + c];
            float4 r = {h.x * dvv, h.y * dvv, h.z * dvv, h.w * dvv};
            z0[(size_t)nd * 16 + c] = f4_to_h4(r);
        }
    }
    if (b == 0 && t < 16) z0[(size_t)N * 16 + t] = make_ushort4(0, 0, 0, 0);
}

// ---------------------------------------------------------------------------
// Degree-binned permutation: block-local counting sort of PB_CHUNK nodes by
// nbatch (= meta.x & 255). Keeps each wave's node-pairs at uniform gather
// trip counts. Tail slots filled with -1.
// ---------------------------------------------------------------------------
__global__ __launch_bounds__(TPB) void p5_perm(const int2* __restrict__ meta,
                                               int* __restrict__ perm,
                                               int N, int slots) {
    __shared__ int cnt[TPB];
    __shared__ int ssc[TPB];
    __shared__ int cur[TPB];
    int t = threadIdx.x;
    int s0 = blockIdx.x * PB_CHUNK;
    int s1 = s0 + PB_CHUNK < N ? s0 + PB_CHUNK : N;
    cnt[t] = 0;
    __syncthreads();
    for (int i = s0 + t; i < s1; i += TPB)
        atomicAdd(&cnt[meta[i].x & 255], 1);
    __syncthreads();
    int v = cnt[t];
    ssc[t] = v;
    __syncthreads();
    for (int off = 1; off < TPB; off <<= 1) {
        int u = 0;
        if (t >= off) u = ssc[t - off];
        __syncthreads();
        ssc[t] += u;
        __syncthreads();
    }
    cur[t] = s0 + ssc[t] - v;                    // block-local bin base
    __syncthreads();
    for (int i = s0 + t; i < s1; i += TPB) {
        int pos = atomicAdd(&cur[meta[i].x & 255], 1);
        perm[pos] = i;
    }
    if (s0 < N && s1 == N)                       // covering block fills tail
        for (int i = N + t; i < slots; i += TPB) perm[i] = -1;
}

// One 8-row gather batch for one node (8 lanes; lane c holds row-chunk c).
__device__ __forceinline__ void gather8(const u16x8* __restrict__ z8,
                                        int idx, int c, int base, f32x8& acc) {
    #pragma unroll
    for (int k = 0; k < 8; ++k) {
        int s = __shfl(idx, base + k);
        u16x8 v = z8[(size_t)s * 8 + c];
        #pragma unroll
        for (int i = 0; i < 8; ++i)
            acc[i] += __half2float(__ushort_as_half(v[i]));
    }
}

// Dual-node cooperative gather: interleaves node a and node b batches for
// 2x memory-level parallelism; next batch's CSR indices prefetched.
__device__ __forceinline__ void gather_pair(const u16x8* __restrict__ z8,
                                            const int* __restrict__ csr,
                                            int sa, int nba, int sb, int nbb,
                                            int c, f32x8& aa, f32x8& ab) {
    const int base = threadIdx.x & 56;           // 8-lane group base in wave
    int btmax = nba > nbb ? nba : nbb;
    int idxa = (nba > 0) ? csr[sa + c] : 0;
    int idxb = (nbb > 0) ? csr[sb + c] : 0;
    for (int bt = 0; bt < btmax; ++bt) {
        int nidxa = (bt + 1 < nba) ? csr[sa + (bt + 1) * 8 + c] : 0;
        int nidxb = (bt + 1 < nbb) ? csr[sb + (bt + 1) * 8 + c] : 0;
        if (bt < nba) gather8(z8, idxa, c, base, aa);
        if (bt < nbb) gather8(z8, idxb, c, base, ab);
        idxa = nidxa;
        idxb = nidxb;
    }
}

// Dual-node shfl mm: one W LDS read (2 float4s) feeds FMAs for BOTH nodes.
// q-loop unroll capped at 2: bounds the ds_read hoisting window (~32 regs)
// -- the R5 full unroll let the scheduler hoist all 128 reads -> VGPR=256
// -> scratch spill (124MB/dispatch). Per-node summation order unchanged.
__device__ __forceinline__ void shfl_mm8_pair(const f32x8& sa, const f32x8& sb,
                                              const float4* Ws4, int c,
                                              f32x8& ua, f32x8& ub) {
    const int base = threadIdx.x & 56;
    #pragma unroll 2
    for (int q = 0; q < 8; ++q) {
        #pragma unroll
        for (int r = 0; r < 8; ++r) {
            float4 w0 = Ws4[(q * 8 + r) * 16 + 2 * c];
            float4 w1 = Ws4[(q * 8 + r) * 16 + 2 * c + 1];
            float ha = __shfl(sa[r], base + q);  // feature q*8+r, node a
            float hb = __shfl(sb[r], base + q);  // feature q*8+r, node b
            ua[0] = fmaf(ha, w0.x, ua[0]);  ub[0] = fmaf(hb, w0.x, ub[0]);
            ua[1] = fmaf(ha, w0.y, ua[1]);  ub[1] = fmaf(hb, w0.y, ub[1]);
            ua[2] = fmaf(ha, w0.z, ua[2]);  ub[2] = fmaf(hb, w0.z, ub[2]);
            ua[3] = fmaf(ha, w0.w, ua[3]);  ub[3] = fmaf(hb, w0.w, ub[3]);
            ua[4] = fmaf(ha, w1.x, ua[4]);  ub[4] = fmaf(hb, w1.x, ub[4]);
            ua[5] = fmaf(ha, w1.y, ua[5]);  ub[5] = fmaf(hb, w1.y, ub[5]);
            ua[6] = fmaf(ha, w1.z, ua[6]);  ub[6] = fmaf(hb, w1.z, ub[6]);
            ua[7] = fmaf(ha, w1.w, ua[7]);  ub[7] = fmaf(hb, w1.w, ub[7]);
        }
    }
}

__device__ __forceinline__ u16x8 f8_to_h8(f32x8 v) {
    u16x8 r;
    #pragma unroll
    for (int i = 0; i < 8; ++i)
        r[i] = __half_as_ushort(__float2half_rn(v[i]));
    return r;
}

__device__ __forceinline__ f32x8 relu_scale(const f32x8& u, float dv,
                                            float4 b0, float4 b1, float post) {
    f32x8 r;
    r[0] = fmaxf(fmaf(dv, u[0], b0.x), 0.f) * post;
    r[1] = fmaxf(fmaf(dv, u[1], b0.y), 0.f) * post;
    r[2] = fmaxf(fmaf(dv, u[2], b0.z), 0.f) * post;
    r[3] = fmaxf(fmaf(dv, u[3], b0.w), 0.f) * post;
    r[4] = fmaxf(fmaf(dv, u[4], b1.x), 0.f) * post;
    r[5] = fmaxf(fmaf(dv, u[5], b1.y), 0.f) * post;
    r[6] = fmaxf(fmaf(dv, u[6], b1.z), 0.f) * post;
    r[7] = fmaxf(fmaf(dv, u[7], b1.w), 0.f) * post;
    return r;
}

// ---------------------------------------------------------------------------
// Layer: s = z_v + Agg z_u (gather); u = s @ W; zout = fp16(dis*relu(dis*u+b)).
// 64 nodes/block: each 8-lane group owns TWO nodes (slots s0+g, s0+8+g).
// W in LDS (16 KB); one W read serves both nodes' FMA streams.
// __launch_bounds__(256,3): cap VGPR ~168 (grid gives ~3 blocks/CU anyway).
// ---------------------------------------------------------------------------
__global__ __launch_bounds__(TPB, 3) void layer_mm(const u16x8* __restrict__ z,
                                                const int* __restrict__ csr,
                                                const int2* __restrict__ meta,
                                                const int* __restrict__ perm,
                                                const float* __restrict__ b,
                                                const float* __restrict__ W,
                                                u16x8* __restrict__ zout, int n) {
    __shared__ float Ws[64 * 64];
    int t = threadIdx.x;
    float4* Ws4 = (float4*)Ws;
    const float4* W4g = (const float4*)W;
    #pragma unroll
    for (int i = 0; i < 4; ++i) Ws4[t + i * TPB] = W4g[t + i * TPB];

    if (blockIdx.x == 0 && t < 8) {              // zero row N for next layer
        u16x8 zz = {0, 0, 0, 0, 0, 0, 0, 0};
        zout[(size_t)n * 8 + t] = zz;
    }

    int wave = t >> 6, lane = t & 63;
    int g = lane >> 3, c = lane & 7;
    int s0 = blockIdx.x * 64 + wave * 16;
    int na = perm[s0 + g];
    int nb = perm[s0 + 8 + g];
    f32x8 sa = {0.f, 0.f, 0.f, 0.f, 0.f, 0.f, 0.f, 0.f};
    f32x8 sb = {0.f, 0.f, 0.f, 0.f, 0.f, 0.f, 0.f, 0.f};
    float dva = 0.f, dvb = 0.f;
    int sta = 0, nba = 0, stb = 0, nbb = 0;
    if (na >= 0) {
        int2 m = meta[na];
        sta = ((unsigned)m.x) >> 8;
        nba = m.x & 255;
        dva = __int_as_float(m.y);
        u16x8 v = z[(size_t)na * 8 + c];         // self-loop term z_a
        #pragma unroll
        for (int i = 0; i < 8; ++i) sa[i] = __half2float(__ushort_as_half(v[i]));
    }
    if (nb >= 0) {
        int2 m = meta[nb];
        stb = ((unsigned)m.x) >> 8;
        nbb = m.x & 255;
        dvb = __int_as_float(m.y);
        u16x8 v = z[(size_t)nb * 8 + c];         // self-loop term z_b
        #pragma unroll
        for (int i = 0; i < 8; ++i) sb[i] = __half2float(__ushort_as_half(v[i]));
    }
    gather_pair(z, csr, sta, nba, stb, nbb, c, sa, sb);
    __syncthreads();                             // Ws fully staged
    f32x8 ua = {0.f, 0.f, 0.f, 0.f, 0.f, 0.f, 0.f, 0.f};
    f32x8 ub = {0.f, 0.f, 0.f, 0.f, 0.f, 0.f, 0.f, 0.f};
    shfl_mm8_pair(sa, sb, Ws4, c, ua, ub);
    float4 b0 = ((const float4*)b)[2 * c];
    float4 b1 = ((const float4*)b)[2 * c + 1];
    if (na >= 0) zout[(size_t)na * 8 + c] = f8_to_h8(relu_scale(ua, dva, b0, b1, dva));
    if (nb >= 0) zout[(size_t)nb * 8 + c] = f8_to_h8(relu_scale(ub, dvb, b0, b1, dvb));
}

// ---------------------------------------------------------------------------
// Final: s = gather(z2); h = relu(dis*(s@W2)+b2); out = h @ linW + linb.
// Dual-node like layer_mm; second mm (64->8) also shares Wls reads.
// ---------------------------------------------------------------------------
__global__ __launch_bounds__(TPB, 3) void layer_final(const u16x8* __restrict__ z,
                                                   const int* __restrict__ csr,
                                                   const int2* __restrict__ meta,
                                                   const int* __restrict__ perm,
                                                   const float* __restrict__ b,
                                                   const float* __restrict__ W,
                                                   const float* __restrict__ Wl,
                                                   const float* __restrict__ bl,
                                                   float* __restrict__ out, int n) {
    __shared__ float Ws[64 * 64];
    __shared__ float Wls[64 * 8];
    __shared__ float bls[8];
    int t = threadIdx.x;
    float4* Ws4 = (float4*)Ws;
    const float4* W4g = (const float4*)W;
    #pragma unroll
    for (int i = 0; i < 4; ++i) Ws4[t + i * TPB] = W4g[t + i * TPB];
    if (t < 128) ((float4*)Wls)[t] = ((const float4*)Wl)[t];
    if (t < 8) bls[t] = bl[t];

    int wave = t >> 6, lane = t & 63;
    int g = lane >> 3, c = lane & 7;
    int s0 = blockIdx.x * 64 + wave * 16;
    int na = perm[s0 + g];
    int nb = perm[s0 + 8 + g];
    f32x8 sa = {0.f, 0.f, 0.f, 0.f, 0.f, 0.f, 0.f, 0.f};
    f32x8 sb = {0.f, 0.f, 0.f, 0.f, 0.f, 0.f, 0.f, 0.f};
    float dva = 0.f, dvb = 0.f;
    int sta = 0, nba = 0, stb = 0, nbb = 0;
    if (na >= 0) {
        int2 m = meta[na];
        sta = ((unsigned)m.x) >> 8;
        nba = m.x & 255;
        dva = __int_as_float(m.y);
        u16x8 v = z[(size_t)na * 8 + c];
        #pragma unroll
        for (int i = 0; i < 8; ++i) sa[i] = __half2float(__ushort_as_half(v[i]));
    }
    if (nb >= 0) {
        int2 m = meta[nb];
        stb = ((unsigned)m.x) >> 8;
        nbb = m.x & 255;
        dvb = __int_as_float(m.y);
        u16x8 v = z[(size_t)nb * 8 + c];
        #pragma unroll
        for (int i = 0; i < 8; ++i) sb[i] = __half2float(__ushort_as_half(v[i]));
    }
    gather_pair(z, csr, sta, nba, stb, nbb, c, sa, sb);
    __syncthreads();                             // Ws/Wls/bls staged
    f32x8 ua = {0.f, 0.f, 0.f, 0.f, 0.f, 0.f, 0.f, 0.f};
    f32x8 ub = {0.f, 0.f, 0.f, 0.f, 0.f, 0.f, 0.f, 0.f};
    shfl_mm8_pair(sa, sb, Ws4, c, ua, ub);
    float4 b0 = ((const float4*)b)[2 * c];
    float4 b1 = ((const float4*)b)[2 * c + 1];
    f32x8 ha = relu_scale(ua, dva, b0, b1, 1.f);
    f32x8 hb = relu_scale(ub, dvb, b0, b1, 1.f);

    // second mm (64 -> 8): lane c computes output col c for both nodes.
    const int base = t & 56;
    float acca = bls[c], accb = bls[c];
    #pragma unroll 2
    for (int q = 0; q < 8; ++q) {
        #pragma unroll
        for (int r = 0; r < 8; ++r) {
            float wv = Wls[(q * 8 + r) * 8 + c];
            float va = __shfl(ha[r], base + q);  // feature q*8+r, node a
            float vb = __shfl(hb[r], base + q);
            acca = fmaf(va, wv, acca);
            accb = fmaf(vb, wv, accb);
        }
    }
    if (na >= 0) out[(size_t)na * 8 + c] = acca;
    if (nb >= 0) out[(size_t)nb * 8 + c] = accb;
}

extern "C" void kernel_launch(void* const* d_in, const int* in_sizes, int n_in,
                              void* d_out, int out_size, void* d_ws, size_t ws_size,
                              hipStream_t stream) {
    const float* x  = (const float*)d_in[0];
    const void*  ei = d_in[1];
    const float* W0 = (const float*)d_in[2];
    const float* b0 = (const float*)d_in[3];
    const float* W1 = (const float*)d_in[4];
    const float* b1 = (const float*)d_in[5];
    const float* W2 = (const float*)d_in[6];
    const float* b2 = (const float*)d_in[7];
    const float* Wl = (const float*)d_in[8];
    const float* bl = (const float*)d_in[9];

    const long long E = in_sizes[1] / 2;                 // 800000
    const int dh = in_sizes[3];                          // 64
    const int din = in_sizes[2] / dh;                    // 64
    const int N = in_sizes[0] / din;                     // 50000
    const int nb = (N + 255) >> 8;                       // 196 buckets
    const int gL = (N + 63) / 64;                        // 782 (64 nodes/block)
    const int slots = gL * 64;                           // 50048

    // Workspace carve (256-aligned): ~39.4 MB total
    char* ws = (char*)d_ws;
    size_t off = 0;
    auto alloc = [&](size_t bytes) -> char* {
        char* r = ws + off;
        off += (bytes + 255) & ~(size_t)255;
        return r;
    };
    int*   gcur    = (int*)  alloc(1024);
    int2*  meta    = (int2*) alloc((size_t)N * 8);
    int*   perm    = (int*)  alloc((size_t)slots * 4);
    int*   pairs   = (int*)  alloc((size_t)nb * CAP * 4);       // 12.8 MB
    int*   csr     = (int*)  alloc((size_t)nb * CAP * 4);       // 12.8 MB
    u16x8* zbA     = (u16x8*)alloc((size_t)(N + 1) * 64 * 2);   // fp16 rows (+zero row)
    u16x8* zbB     = (u16x8*)alloc((size_t)(N + 1) * 64 * 2);

    // --- preprocessing ---
    hipMemsetAsync(gcur, 0, 256 * sizeof(int), stream);
    p3_scatter<<<SC_BLOCKS, TPB, 0, stream>>>(ei, E, gcur, pairs);
    p4_fill<<<nb, TPB, 0, stream>>>(pairs, gcur, x, meta, csr,
                                    (ushort4*)zbA, N);
    p5_perm<<<PB_BLOCKS, TPB, 0, stream>>>(meta, perm, N, slots);

    // --- 3 layers: gather -> mm -> relu ---
    layer_mm<<<gL, TPB, 0, stream>>>(zbA, csr, meta, perm, b0, W0, zbB, N);
    layer_mm<<<gL, TPB, 0, stream>>>(zbB, csr, meta, perm, b1, W1, zbA, N);
    layer_final<<<gL, TPB, 0, stream>>>(zbA, csr, meta, perm, b2, W2, Wl, bl,
                                        (float*)d_out, N);
}

// Round 7
// 184.968 us; speedup vs baseline: 2.3386x; 1.0761x over previous
//
#include <hip/hip_runtime.h>
#include <hip/hip_fp16.h>

#define TPB 256
#define CAP 16384          // slack entries per 256-node bucket (padded fill ~5100)
#define CAPSH 14           // log2(CAP)
#define SC_BLOCKS 256      // scatter blocks: contiguous pairs chunks per bucket

typedef __attribute__((ext_vector_type(8))) float f32x8;
typedef __attribute__((ext_vector_type(8))) unsigned short u16x8;
typedef __attribute__((ext_vector_type(4))) unsigned int u32x4;
typedef __attribute__((ext_vector_type(2))) _Float16 h16x2;

// Identity used: dis⊙(x@W) = (dis⊙x)@W and Agg(z@W) = (Agg z)@W, so each
// layer is gather(z) -> mm -> relu, with z = fp16(dis ⊙ activation).
// Buckets: 256 nodes each (dst>>8); bucket b owns pairs/csr[b*CAP..).
// CSR runs padded to a multiple of 8 with index N (zero row).
// meta[v] = { (offset<<8) | nbatches, bitcast(dis) }.
// Lessons: R2 direct CSR = 51MB write-allocate (bad). R3 spill fix neutral.
// R4 degree-binning neutral. R5 dual-node spilled (VGPR=256, 124MB scratch).
// R6 spill-fixed dual-node = 199us: per-CU outstanding gather loads are
// invariant under node-batching (waves halve, rows/wave double) -> layers
// sit at a load-latency equilibrium + VALU tail.
// This round (base = R3): (1) cross-batch ping-pong pipeline in gather --
// next batch's 8 rows issue BEFORE current batch accumulates (idx fetched 2
// batches ahead), so row latency hides under VALU and per-wave MLP doubles
// at unchanged occupancy; (2) v_perm+fdot2 pairwise accumulate halves
// gather VALU (f32 accumulation kept; __has_builtin-guarded fallback).

__device__ __forceinline__ int ld_idx(const void* p, long long i, int is64) {
    return is64 ? (int)((const long long*)p)[i] : ((const int*)p)[i];
}

__device__ __forceinline__ ushort4 f4_to_h4(float4 v) {
    ushort4 r;
    r.x = __half_as_ushort(__float2half_rn(v.x));
    r.y = __half_as_ushort(__float2half_rn(v.y));
    r.z = __half_as_ushort(__float2half_rn(v.z));
    r.w = __half_as_ushort(__float2half_rn(v.w));
    return r;
}

// ---------------------------------------------------------------------------
// Scatter: pass A histograms dst buckets (LDS), one global atomic per
// (block,bucket) reserves a contiguous chunk, pass B re-reads edges (L2/L3
// warm) and writes pairs into the chunk. gcur must be zeroed.
// ---------------------------------------------------------------------------
__global__ __launch_bounds__(TPB) void p3_scatter(const void* __restrict__ ei,
                                                  long long E,
                                                  int* __restrict__ gcur,
                                                  int* __restrict__ pairs) {
    __shared__ int cnt[TPB];
    __shared__ int cur2[TPB];
    __shared__ int s_is64;
    int t = threadIdx.x;
    if (t < 64) {
        const unsigned int* w = (const unsigned int*)ei;
        unsigned long long m = __ballot(w[2 * t + 1] != 0u);
        if (t == 0) s_is64 = (m == 0ull) ? 1 : 0;
    }
    cnt[t] = 0;
    __syncthreads();
    const int is64 = s_is64;
    long long chunk = (E + SC_BLOCKS - 1) / SC_BLOCKS;
    long long s0 = (long long)blockIdx.x * chunk;
    long long s1 = (s0 + chunk < E) ? s0 + chunk : E;

    for (long long e = s0 + t; e < s1; e += TPB) {       // pass A: count
        int d = ld_idx(ei, E + e, is64);
        atomicAdd(&cnt[d >> 8], 1);
    }
    __syncthreads();
    if (cnt[t]) cur2[t] = (t << CAPSH) + atomicAdd(&gcur[t], cnt[t]);
    __syncthreads();
    for (long long e = s0 + t; e < s1; e += TPB) {       // pass B: write
        int sv = ld_idx(ei, e, is64);
        int d  = ld_idx(ei, E + e, is64);
        int pos = atomicAdd(&cur2[d >> 8], 1);
        pairs[pos] = (sv << 8) | (d & 255);
    }
}

// ---------------------------------------------------------------------------
// One block per bucket: degree count (LDS atomics) -> pad-to-8 256-wide scan
// -> meta, csr scatter via LDS cursors + pad with index N, then
// z0 = fp16(dis * x) for this bucket's 256 nodes. Block 0 zeroes z0 row N.
// ---------------------------------------------------------------------------
__global__ __launch_bounds__(TPB) void p4_fill(const int* __restrict__ pairs,
                                               const int* __restrict__ gcur,
                                               const float* __restrict__ x,
                                               int2* __restrict__ meta,
                                               int* __restrict__ csr,
                                               ushort4* __restrict__ z0, int N) {
    __shared__ int ldeg[TPB];
    __shared__ int ssc[TPB];
    __shared__ int cur[TPB];
    __shared__ float fdis[TPB];
    int t = threadIdx.x;
    int b = blockIdx.x;
    int base = b << CAPSH;
    int ecnt = gcur[b];                          // real edges in this bucket
    ldeg[t] = 0;
    __syncthreads();
    for (int e = base + t; e < base + ecnt; e += TPB)
        atomicAdd(&ldeg[pairs[e] & 255], 1);
    __syncthreads();
    int dv = ldeg[t];
    int pv = (dv + 7) & ~7;                      // padded to multiple of 8
    ssc[t] = pv;
    __syncthreads();
    for (int off = 1; off < TPB; off <<= 1) {
        int u = 0;
        if (t >= off) u = ssc[t - off];
        __syncthreads();
        ssc[t] += u;
        __syncthreads();
    }
    int o = base + ssc[t] - pv;                  // absolute padded offset
    cur[t] = o;
    float dd = rsqrtf((float)(dv + 1));          // +1 self loop
    fdis[t] = dd;
    int node = (b << 8) + t;
    if (node < N)
        meta[node] = make_int2((o << 8) | (pv >> 3), __float_as_int(dd));
    __syncthreads();
    for (int e = base + t; e < base + ecnt; e += TPB) {
        int p = pairs[e];
        int pos = atomicAdd(&cur[p & 255], 1);
        csr[pos] = p >> 8;
    }
    for (int e = o + dv; e < o + pv; ++e) csr[e] = N;   // pad with zero row

    // z0 conversion: 16 passes, 16 nodes each, coalesced float4 reads.
    int ni = t >> 4, c = t & 15;
    for (int p = 0; p < 16; ++p) {
        int nd = (b << 8) + p * 16 + ni;
        if (nd < N) {
            float dvv = fdis[p * 16 + ni];
            float4 h = ((const float4*)x)[(size_t)nd * 16 + c];
            float4 r = {h.x * dvv, h.y * dvv, h.z * dvv, h.w * dvv};
            z0[(size_t)nd * 16 + c] = f4_to_h4(r);
        }
    }
    if (b == 0 && t < 16) z0[(size_t)N * 16 + t] = make_ushort4(0, 0, 0, 0);
}

// ---------------------------------------------------------------------------
// Gather building blocks
// ---------------------------------------------------------------------------

#if __has_builtin(__builtin_amdgcn_fdot2) && __has_builtin(__builtin_amdgcn_perm)
#define GCN_DOT2 1
#else
#define GCN_DOT2 0
#endif

// Accumulate the 8 features of TWO fp16 rows into f32 acc.
// perm packs (rowA.h_j, rowB.h_j) into one half2; fdot2 with (1,1) adds both
// halves into the f32 accumulator: 4 inst per 2 rows x 2 features (vs 8).
__device__ __forceinline__ void accum_row_pair(const u16x8& ra, const u16x8& rb,
                                               f32x8& acc) {
#if GCN_DOT2
    u32x4 a = __builtin_bit_cast(u32x4, ra);
    u32x4 b = __builtin_bit_cast(u32x4, rb);
    const h16x2 one = {(_Float16)1.0f, (_Float16)1.0f};
    #pragma unroll
    for (int j = 0; j < 4; ++j) {
        unsigned p0 = __builtin_amdgcn_perm(a[j], b[j], 0x05040100u); // h0 pair
        unsigned p1 = __builtin_amdgcn_perm(a[j], b[j], 0x07060302u); // h1 pair
        acc[2 * j]     = __builtin_amdgcn_fdot2(__builtin_bit_cast(h16x2, p0),
                                                one, acc[2 * j], false);
        acc[2 * j + 1] = __builtin_amdgcn_fdot2(__builtin_bit_cast(h16x2, p1),
                                                one, acc[2 * j + 1], false);
    }
#else
    #pragma unroll
    for (int i = 0; i < 8; ++i)
        acc[i] += __half2float(__ushort_as_half(ra[i])) +
                  __half2float(__ushort_as_half(rb[i]));
#endif
}

__device__ __forceinline__ void accum_batch(const u16x8 (&R)[8], f32x8& acc) {
    #pragma unroll
    for (int k = 0; k < 8; k += 2) accum_row_pair(R[k], R[k + 1], acc);
}

// Issue the 8 independent 16B row-chunk loads of one batch (indices via shfl
// from the 8-lane group's coalesced csr read). Fully unrolled: static regs.
__device__ __forceinline__ void load_batch(const u16x8* __restrict__ z8,
                                           u16x8 (&R)[8], int idx, int c,
                                           int base) {
    #pragma unroll
    for (int k = 0; k < 8; ++k) {
        int s = __shfl(idx, base + k);
        R[k] = z8[(size_t)s * 8 + c];
    }
}

// Pipelined cooperative gather (PADDED csr): ping-pong row buffers A/B.
// While batch bt accumulates (VALU), batch bt+1's 8 row loads are already in
// flight; csr indices are prefetched 2 batches ahead so the shfl never waits
// on a fresh csr load. Doubles per-wave outstanding rows at same occupancy.
__device__ __forceinline__ f32x8 gather_rows(const u16x8* __restrict__ z8,
                                             const int* __restrict__ csr,
                                             int start, int nbatch, int c,
                                             f32x8 acc) {
    const int base = threadIdx.x & 56;           // 8-lane group base in wave
    if (nbatch <= 0) return acc;
    u16x8 A[8], B[8];
    int idx0 = csr[start + c];
    int idx_n = (nbatch > 1) ? csr[start + 8 + c] : 0;   // batch 1 idx
    load_batch(z8, A, idx0, c, base);
    int bt = 0;
    for (;;) {
        // invariant: A = rows of batch bt, idx_n = csr idx of batch bt+1
        int idx_f = (bt + 2 < nbatch) ? csr[start + (bt + 2) * 8 + c] : 0;
        if (bt + 1 < nbatch) load_batch(z8, B, idx_n, c, base);
        accum_batch(A, acc);
        if (++bt >= nbatch) break;
        // B = rows of batch bt, idx_f = csr idx of batch bt+1
        int idx_f2 = (bt + 2 < nbatch) ? csr[start + (bt + 2) * 8 + c] : 0;
        if (bt + 1 < nbatch) load_batch(z8, A, idx_f, c, base);
        accum_batch(B, acc);
        if (++bt >= nbatch) break;
        idx_n = idx_f2;
    }
    return acc;
}

// Shfl-based mm for 8-lane groups: lane c holds features 8c..8c+7 of its
// node (f32x8); broadcast via __shfl; lane c accumulates output cols
// 8c..8c+7. Per-k Ws reads are 2 consecutive float4s (256 B/group contiguous,
// broadcast across groups -> conflict-free).
__device__ __forceinline__ f32x8 shfl_mm8(f32x8 s, const float4* Ws4, int c) {
    const int base = threadIdx.x & 56;
    f32x8 u = {0.f, 0.f, 0.f, 0.f, 0.f, 0.f, 0.f, 0.f};
    #pragma unroll
    for (int q = 0; q < 8; ++q) {
        #pragma unroll
        for (int r = 0; r < 8; ++r) {
            float hv = __shfl(s[r], base + q);   // feature q*8+r
            float4 w0 = Ws4[(q * 8 + r) * 16 + 2 * c];
            float4 w1 = Ws4[(q * 8 + r) * 16 + 2 * c + 1];
            u[0] = fmaf(hv, w0.x, u[0]);
            u[1] = fmaf(hv, w0.y, u[1]);
            u[2] = fmaf(hv, w0.z, u[2]);
            u[3] = fmaf(hv, w0.w, u[3]);
            u[4] = fmaf(hv, w1.x, u[4]);
            u[5] = fmaf(hv, w1.y, u[5]);
            u[6] = fmaf(hv, w1.z, u[6]);
            u[7] = fmaf(hv, w1.w, u[7]);
        }
    }
    return u;
}

__device__ __forceinline__ u16x8 f8_to_h8(f32x8 v) {
    u16x8 r;
    #pragma unroll
    for (int i = 0; i < 8; ++i)
        r[i] = __half_as_ushort(__float2half_rn(v[i]));
    return r;
}

// ---------------------------------------------------------------------------
// Layer: s = z_v + Agg z_u (gather); u = s @ W; zout = fp16(dis*relu(dis*u+b)).
// 32 nodes/block, 8 threads/node. Only W in LDS (16 KB).
// ---------------------------------------------------------------------------
__global__ __launch_bounds__(TPB) void layer_mm(const u16x8* __restrict__ z,
                                                const int* __restrict__ csr,
                                                const int2* __restrict__ meta,
                                                const float* __restrict__ b,
                                                const float* __restrict__ W,
                                                u16x8* __restrict__ zout, int n) {
    __shared__ float Ws[64 * 64];
    int t = threadIdx.x;
    float4* Ws4 = (float4*)Ws;
    const float4* W4g = (const float4*)W;
    #pragma unroll
    for (int i = 0; i < 4; ++i) Ws4[t + i * TPB] = W4g[t + i * TPB];

    if (blockIdx.x == 0 && t < 8) {              // zero row N for next layer
        u16x8 zz = {0, 0, 0, 0, 0, 0, 0, 0};
        zout[(size_t)n * 8 + t] = zz;
    }

    int wave = t >> 6, lane = t & 63;
    int g = lane >> 3, c = lane & 7;
    int node = blockIdx.x * 32 + wave * 8 + g;
    f32x8 s = {0.f, 0.f, 0.f, 0.f, 0.f, 0.f, 0.f, 0.f};
    float dv = 0.f;
    if (node < n) {
        int2 m = meta[node];
        int start = ((unsigned)m.x) >> 8;
        int nbatch = m.x & 255;
        dv = __int_as_float(m.y);
        u16x8 v = z[(size_t)node * 8 + c];       // self-loop term z_v
        #pragma unroll
        for (int i = 0; i < 8; ++i) s[i] = __half2float(__ushort_as_half(v[i]));
        s = gather_rows(z, csr, start, nbatch, c, s);
    }
    __syncthreads();                             // Ws fully staged
    f32x8 u = shfl_mm8(s, Ws4, c);
    if (node < n) {
        float4 b0 = ((const float4*)b)[2 * c];
        float4 b1 = ((const float4*)b)[2 * c + 1];
        f32x8 r;
        r[0] = fmaxf(fmaf(dv, u[0], b0.x), 0.f) * dv;
        r[1] = fmaxf(fmaf(dv, u[1], b0.y), 0.f) * dv;
        r[2] = fmaxf(fmaf(dv, u[2], b0.z), 0.f) * dv;
        r[3] = fmaxf(fmaf(dv, u[3], b0.w), 0.f) * dv;
        r[4] = fmaxf(fmaf(dv, u[4], b1.x), 0.f) * dv;
        r[5] = fmaxf(fmaf(dv, u[5], b1.y), 0.f) * dv;
        r[6] = fmaxf(fmaf(dv, u[6], b1.z), 0.f) * dv;
        r[7] = fmaxf(fmaf(dv, u[7], b1.w), 0.f) * dv;
        zout[(size_t)node * 8 + c] = f8_to_h8(r);    // z_{l+1}
    }
}

// ---------------------------------------------------------------------------
// Final: s = gather(z2); h = relu(dis*(s@W2)+b2); out = h @ linW + linb.
// Second mm: lane c computes output col c (all 8 lanes active).
// ---------------------------------------------------------------------------
__global__ __launch_bounds__(TPB) void layer_final(const u16x8* __restrict__ z,
                                                   const int* __restrict__ csr,
                                                   const int2* __restrict__ meta,
                                                   const float* __restrict__ b,
                                                   const float* __restrict__ W,
                                                   const float* __restrict__ Wl,
                                                   const float* __restrict__ bl,
                                                   float* __restrict__ out, int n) {
    __shared__ float Ws[64 * 64];
    __shared__ float Wls[64 * 8];
    __shared__ float bls[8];
    int t = threadIdx.x;
    float4* Ws4 = (float4*)Ws;
    const float4* W4g = (const float4*)W;
    #pragma unroll
    for (int i = 0; i < 4; ++i) Ws4[t + i * TPB] = W4g[t + i * TPB];
    if (t < 128) ((float4*)Wls)[t] = ((const float4*)Wl)[t];
    if (t < 8) bls[t] = bl[t];

    int wave = t >> 6, lane = t & 63;
    int g = lane >> 3, c = lane & 7;
    int node = blockIdx.x * 32 + wave * 8 + g;
    f32x8 s = {0.f, 0.f, 0.f, 0.f, 0.f, 0.f, 0.f, 0.f};
    float dv = 0.f;
    if (node < n) {
        int2 m = meta[node];
        int start = ((unsigned)m.x) >> 8;
        int nbatch = m.x & 255;
        dv = __int_as_float(m.y);
        u16x8 v = z[(size_t)node * 8 + c];
        #pragma unroll
        for (int i = 0; i < 8; ++i) s[i] = __half2float(__ushort_as_half(v[i]));
        s = gather_rows(z, csr, start, nbatch, c, s);
    }
    __syncthreads();                             // Ws/Wls/bls staged
    f32x8 u = shfl_mm8(s, Ws4, c);
    float4 b0 = ((const float4*)b)[2 * c];
    float4 b1 = ((const float4*)b)[2 * c + 1];
    f32x8 h;
    h[0] = fmaxf(fmaf(dv, u[0], b0.x), 0.f);
    h[1] = fmaxf(fmaf(dv, u[1], b0.y), 0.f);
    h[2] = fmaxf(fmaf(dv, u[2], b0.z), 0.f);
    h[3] = fmaxf(fmaf(dv, u[3], b0.w), 0.f);
    h[4] = fmaxf(fmaf(dv, u[4], b1.x), 0.f);
    h[5] = fmaxf(fmaf(dv, u[5], b1.y), 0.f);
    h[6] = fmaxf(fmaf(dv, u[6], b1.z), 0.f);
    h[7] = fmaxf(fmaf(dv, u[7], b1.w), 0.f);

    // second mm (64 -> 8): lane c computes output col c.
    const int base = threadIdx.x & 56;
    float acc = bls[c];
    #pragma unroll
    for (int q = 0; q < 8; ++q) {
        #pragma unroll
        for (int r = 0; r < 8; ++r) {
            float hv = __shfl(h[r], base + q);   // feature q*8+r
            acc = fmaf(hv, Wls[(q * 8 + r) * 8 + c], acc);
        }
    }
    if (node < n) out[(size_t)node * 8 + c] = acc;
}

extern "C" void kernel_launch(void* const* d_in, const int* in_sizes, int n_in,
                              void* d_out, int out_size, void* d_ws, size_t ws_size,
                              hipStream_t stream) {
    const float* x  = (const float*)d_in[0];
    const void*  ei = d_in[1];
    const float* W0 = (const float*)d_in[2];
    const float* b0 = (const float*)d_in[3];
    const float* W1 = (const float*)d_in[4];
    const float* b1 = (const float*)d_in[5];
    const float* W2 = (const float*)d_in[6];
    const float* b2 = (const float*)d_in[7];
    const float* Wl = (const float*)d_in[8];
    const float* bl = (const float*)d_in[9];

    const long long E = in_sizes[1] / 2;                 // 800000
    const int dh = in_sizes[3];                          // 64
    const int din = in_sizes[2] / dh;                    // 64
    const int N = in_sizes[0] / din;                     // 50000
    const int nb = (N + 255) >> 8;                       // 196 buckets

    // Workspace carve (256-aligned): ~39 MB total
    char* ws = (char*)d_ws;
    size_t off = 0;
    auto alloc = [&](size_t bytes) -> char* {
        char* r = ws + off;
        off += (bytes + 255) & ~(size_t)255;
        return r;
    };
    int*   gcur    = (int*)  alloc(1024);
    int2*  meta    = (int2*) alloc((size_t)N * 8);
    int*   pairs   = (int*)  alloc((size_t)nb * CAP * 4);       // 12.8 MB
    int*   csr     = (int*)  alloc((size_t)nb * CAP * 4);       // 12.8 MB
    u16x8* zbA     = (u16x8*)alloc((size_t)(N + 1) * 64 * 2);   // fp16 rows (+zero row)
    u16x8* zbB     = (u16x8*)alloc((size_t)(N + 1) * 64 * 2);

    // --- preprocessing ---
    hipMemsetAsync(gcur, 0, 256 * sizeof(int), stream);
    p3_scatter<<<SC_BLOCKS, TPB, 0, stream>>>(ei, E, gcur, pairs);
    p4_fill<<<nb, TPB, 0, stream>>>(pairs, gcur, x, meta, csr,
                                    (ushort4*)zbA, N);

    // --- 3 layers: gather -> mm -> relu ---
    const int gL = (N + 31) / 32;                        // 1563
    layer_mm<<<gL, TPB, 0, stream>>>(zbA, csr, meta, b0, W0, zbB, N);
    layer_mm<<<gL, TPB, 0, stream>>>(zbB, csr, meta, b1, W1, zbA, N);
    layer_final<<<gL, TPB, 0, stream>>>(zbA, csr, meta, b2, W2, Wl, bl,
                                        (float*)d_out, N);
}